// Round 1
// baseline (840.190 us; speedup 1.0000x reference)
//
#include <hip/hip_runtime.h>
#include <hip/hip_bf16.h>

#define BSZ 4
#define CC 64
#define NN 4096
#define CN (CC*NN)        // 262144
#define BCN (BSZ*CN)      // 1048576

// ---------------------------------------------------------------------------
// K1: gram matrix G[i2][b][c][d] = sum_n X[c,n]*X[d,n]   (X = cnn or vit)
// one thread per output element; rows stream from L2 (whole problem ~8MB).
__global__ __launch_bounds__(256) void gram_k(const float* __restrict__ cnn,
                                              const float* __restrict__ vit,
                                              float* __restrict__ G) {
    int idx = blockIdx.x * 256 + threadIdx.x;          // 2*B*C*C = 32768
    int d  = idx & 63;
    int c  = (idx >> 6) & 63;
    int b  = (idx >> 12) & 3;
    int i2 = idx >> 14;
    const float* X = (i2 ? vit : cnn) + b * CN;
    const float4* xc = (const float4*)(X + c * NN);
    const float4* xd = (const float4*)(X + d * NN);
    float s0 = 0.f, s1 = 0.f, s2 = 0.f, s3 = 0.f;
    for (int n = 0; n < NN / 4; n += 4) {
        float4 a0 = xc[n + 0], b0 = xd[n + 0];
        float4 a1 = xc[n + 1], b1 = xd[n + 1];
        float4 a2 = xc[n + 2], b2 = xd[n + 2];
        float4 a3 = xc[n + 3], b3 = xd[n + 3];
        s0 += a0.x * b0.x + a0.y * b0.y + a0.z * b0.z + a0.w * b0.w;
        s1 += a1.x * b1.x + a1.y * b1.y + a1.z * b1.z + a1.w * b1.w;
        s2 += a2.x * b2.x + a2.y * b2.y + a2.z * b2.z + a2.w * b2.w;
        s3 += a3.x * b3.x + a3.y * b3.y + a3.z * b3.z + a3.w * b3.w;
    }
    G[idx] = (s0 + s1) + (s2 + s3);
}

// ---------------------------------------------------------------------------
// K2: channel softmax, in place on G.
// softmax over d of (rowmax - G) == exp(rowmin - G) / sum(exp(rowmin - G))
__global__ void csoft_k(float* __restrict__ G) {
    int r = blockIdx.x * 64 + threadIdx.x;             // 2*B*C = 512 rows
    float* row = G + r * 64;
    float mn = 1e30f;
    for (int i = 0; i < 64; i++) mn = fminf(mn, row[i]);
    float sum = 0.f;
    for (int i = 0; i < 64; i++) {
        float e = expf(mn - row[i]);
        row[i] = e;
        sum += e;
    }
    float inv = 1.f / sum;
    for (int i = 0; i < 64; i++) row[i] *= inv;
}

// ---------------------------------------------------------------------------
// K3: att[i2][b][c][n] = g_i2 * sum_d A[c,d]*X[d,n] + X[c,n]
__global__ __launch_bounds__(256) void capply_k(const float* __restrict__ cnn,
                                                const float* __restrict__ vit,
                                                const float* __restrict__ G,
                                                const float* __restrict__ gcnn,
                                                const float* __restrict__ gvit,
                                                float* __restrict__ att) {
    int idx = blockIdx.x * 256 + threadIdx.x;          // 2*B*C*N = 2^21
    int n  = idx & (NN - 1);
    int c  = (idx >> 12) & 63;
    int b  = (idx >> 18) & 3;
    int i2 = idx >> 20;
    const float* X = (i2 ? vit : cnn) + b * CN;
    const float* A = G + (i2 * 4 + b) * 4096 + c * 64;
    float s = 0.f;
#pragma unroll 8
    for (int d = 0; d < 64; d++) s += A[d] * X[d * NN + n];
    float g = i2 ? *gvit : *gcnn;
    att[idx] = g * s + X[c * NN + n];
}

// ---------------------------------------------------------------------------
// K4: fused QKV projections.
// q[b,n,o] = sum_c cnn_att[b,c,n]*Wq[o,c] + bq[o]        (o < 8)
// k[b,n,o] = sum_c vit_att[b,c,n]*Wk[o,c] + bk[o]
// v[b,n,j] = sum_c vit_att[b,c,n]*Wv[j,c] + bv[j]        (j < 64)
__global__ __launch_bounds__(256) void qkv_k(const float* __restrict__ att,
                                             const float* __restrict__ Wq, const float* __restrict__ bq,
                                             const float* __restrict__ Wk, const float* __restrict__ bk,
                                             const float* __restrict__ Wv, const float* __restrict__ bv,
                                             float* __restrict__ q, float* __restrict__ kk,
                                             float* __restrict__ v) {
    __shared__ float sWq[512], sWk[512], sWv[4096], sbq[8], sbk[8], sbv[64];
    int t = threadIdx.x;
    for (int i = t; i < 512; i += 256) { sWq[i] = Wq[i]; sWk[i] = Wk[i]; }
    for (int i = t; i < 4096; i += 256) sWv[i] = Wv[i];
    if (t < 8) { sbq[t] = bq[t]; sbk[t] = bk[t]; }
    if (t < 64) sbv[t] = bv[t];
    __syncthreads();

    int gid = blockIdx.x * 256 + t;                    // B*N = 16384
    int n = gid & (NN - 1);
    int b = gid >> 12;
    const float* xc = att + b * CN + n;                // cnn_att
    const float* xv = att + BCN + b * CN + n;          // vit_att

    float aq[8], ak[8], av[64];
#pragma unroll
    for (int o = 0; o < 8; o++) { aq[o] = sbq[o]; ak[o] = sbk[o]; }
#pragma unroll
    for (int j = 0; j < 64; j++) av[j] = sbv[j];

    for (int c = 0; c < 64; c++) {
        float a = xc[c * NN];
        float w = xv[c * NN];
#pragma unroll
        for (int o = 0; o < 8; o++) { aq[o] += a * sWq[o * 64 + c]; ak[o] += w * sWk[o * 64 + c]; }
#pragma unroll
        for (int j = 0; j < 64; j++) av[j] += w * sWv[j * 64 + c];
    }
#pragma unroll
    for (int o = 0; o < 8; o++) { q[gid * 8 + o] = aq[o]; kk[gid * 8 + o] = ak[o]; }
#pragma unroll
    for (int j = 0; j < 64; j++) v[gid * 64 + j] = av[j];
}

// ---------------------------------------------------------------------------
// K5: flash attention. Per block: batch b, 64 query rows. 256 threads:
// thread (rg = t>>3, g = t&7) owns rows {rg, rg+32} and cols j = g*8..g*8+8.
// Online softmax with per-row m,l replicated across the row's 8 lanes.
__global__ __launch_bounds__(256) void flash_k(const float* __restrict__ q,
                                               const float* __restrict__ kk,
                                               const float* __restrict__ v,
                                               float* __restrict__ O) {
    int b  = blockIdx.x >> 6;                          // 4 * 64 blocks
    int q0 = (blockIdx.x & 63) * 64;
    __shared__ float Kt[64][8];
    __shared__ float Vt[64][68];                       // 68: rows 16B-aligned, <=2-way banks
    __shared__ float P[64][68];
    int t = threadIdx.x;
    int rg = t >> 3, g = t & 7;
    int r0 = rg, r1 = rg + 32;

    float Q0[8], Q1[8];
#pragma unroll
    for (int o = 0; o < 8; o++) {
        Q0[o] = q[(b * NN + q0 + r0) * 8 + o];
        Q1[o] = q[(b * NN + q0 + r1) * 8 + o];
    }
    float m0 = -1e30f, m1 = -1e30f, l0 = 0.f, l1 = 0.f;
    float acc0[8], acc1[8];
#pragma unroll
    for (int u = 0; u < 8; u++) { acc0[u] = 0.f; acc1[u] = 0.f; }

    for (int kt = 0; kt < 64; kt++) {
        int k0 = kt * 64;
        __syncthreads();                               // prior-iter Vt reads done
        for (int i = t; i < 512; i += 256)
            Kt[i >> 3][i & 7] = kk[(b * NN + k0 + (i >> 3)) * 8 + (i & 7)];
        for (int i = t; i < 4096; i += 256)
            Vt[i >> 6][i & 63] = v[(b * NN + k0 + (i >> 6)) * 64 + (i & 63)];
        __syncthreads();

        float s0[8], s1[8];
        float mx0 = -1e30f, mx1 = -1e30f;
#pragma unroll
        for (int u = 0; u < 8; u++) {
            int k = g * 8 + u;
            float a0 = 0.f, a1 = 0.f;
#pragma unroll
            for (int o = 0; o < 8; o++) {
                float kv = Kt[k][o];
                a0 += Q0[o] * kv;
                a1 += Q1[o] * kv;
            }
            s0[u] = a0; s1[u] = a1;
            mx0 = fmaxf(mx0, a0); mx1 = fmaxf(mx1, a1);
        }
        // reduce max across the 8 lanes of each row (lanes contiguous in-wave)
        mx0 = fmaxf(mx0, __shfl_xor(mx0, 1)); mx1 = fmaxf(mx1, __shfl_xor(mx1, 1));
        mx0 = fmaxf(mx0, __shfl_xor(mx0, 2)); mx1 = fmaxf(mx1, __shfl_xor(mx1, 2));
        mx0 = fmaxf(mx0, __shfl_xor(mx0, 4)); mx1 = fmaxf(mx1, __shfl_xor(mx1, 4));
        float mn0 = fmaxf(m0, mx0), mn1 = fmaxf(m1, mx1);
        float al0 = __expf(m0 - mn0), al1 = __expf(m1 - mn1);
        float rs0 = 0.f, rs1 = 0.f;
#pragma unroll
        for (int u = 0; u < 8; u++) {
            float p0 = __expf(s0[u] - mn0);
            float p1 = __expf(s1[u] - mn1);
            P[r0][g * 8 + u] = p0;
            P[r1][g * 8 + u] = p1;
            rs0 += p0; rs1 += p1;
        }
        rs0 += __shfl_xor(rs0, 1); rs1 += __shfl_xor(rs1, 1);
        rs0 += __shfl_xor(rs0, 2); rs1 += __shfl_xor(rs1, 2);
        rs0 += __shfl_xor(rs0, 4); rs1 += __shfl_xor(rs1, 4);
        l0 = l0 * al0 + rs0;
        l1 = l1 * al1 + rs1;
        m0 = mn0; m1 = mn1;
#pragma unroll
        for (int u = 0; u < 8; u++) { acc0[u] *= al0; acc1[u] *= al1; }
        // P rows r0/r1 written and read by the same 8 lanes (same wave): no barrier.
        for (int k = 0; k < 64; k++) {
            float p0 = P[r0][k];
            float p1 = P[r1][k];
#pragma unroll
            for (int u = 0; u < 8; u++) {
                float vv = Vt[k][g * 8 + u];
                acc0[u] += p0 * vv;
                acc1[u] += p1 * vv;
            }
        }
    }
    float i0 = 1.f / l0, i1 = 1.f / l1;
#pragma unroll
    for (int u = 0; u < 8; u++) {
        O[(b * NN + q0 + r0) * 64 + g * 8 + u] = acc0[u] * i0;
        O[(b * NN + q0 + r1) * 64 + g * 8 + u] = acc1[u] * i1;
    }
}

// ---------------------------------------------------------------------------
// K6: out[b,c,n] = gamma * O[b,n,c] + cnn[b,c,n]   (transpose via LDS tile)
__global__ __launch_bounds__(256) void epi_k(const float* __restrict__ O,
                                             const float* __restrict__ cnn,
                                             const float* __restrict__ gamma,
                                             float* __restrict__ out) {
    int b  = blockIdx.x >> 6;
    int n0 = (blockIdx.x & 63) * 64;
    __shared__ float T[64][65];
    int t = threadIdx.x;
    for (int i = t; i < 4096; i += 256) {
        int in = i >> 6, c = i & 63;
        T[in][c] = O[(b * NN + n0 + in) * 64 + c];
    }
    __syncthreads();
    float g = *gamma;
    for (int i = t; i < 4096; i += 256) {
        int c = i >> 6, in = i & 63;
        int oidx = (b * 64 + c) * NN + n0 + in;
        out[oidx] = g * T[in][c] + cnn[oidx];
    }
}

// ---------------------------------------------------------------------------
extern "C" void kernel_launch(void* const* d_in, const int* in_sizes, int n_in,
                              void* d_out, int out_size, void* d_ws, size_t ws_size,
                              hipStream_t stream) {
    const float* cnn  = (const float*)d_in[0];
    const float* vit  = (const float*)d_in[1];
    const float* Wq   = (const float*)d_in[2];
    const float* bq   = (const float*)d_in[3];
    const float* Wk   = (const float*)d_in[4];
    const float* bk   = (const float*)d_in[5];
    const float* Wv   = (const float*)d_in[6];
    const float* bv   = (const float*)d_in[7];
    const float* gam  = (const float*)d_in[8];
    const float* gcnn = (const float*)d_in[9];
    const float* gvit = (const float*)d_in[10];
    float* out = (float*)d_out;

    float* ws  = (float*)d_ws;
    float* att = ws;                      // 2*B*C*N      = 2097152 floats
    float* G   = ws + 2097152;            // 2*B*C*C      = 32768
    float* q   = ws + 2129920;            // B*N*8        = 131072
    float* kk  = ws + 2260992;            // B*N*8        = 131072
    float* v   = ws + 2392064;            // B*N*C        = 1048576
    float* O   = ws + 3440640;            // B*N*C        = 1048576
                                          // total ~18 MB

    gram_k  <<<128,  256, 0, stream>>>(cnn, vit, G);
    csoft_k <<<8,    64,  0, stream>>>(G);
    capply_k<<<8192, 256, 0, stream>>>(cnn, vit, G, gcnn, gvit, att);
    qkv_k   <<<64,   256, 0, stream>>>(att, Wq, bq, Wk, bk, Wv, bv, q, kk, v);
    flash_k <<<256,  256, 0, stream>>>(q, kk, v, O);
    epi_k   <<<256,  256, 0, stream>>>(O, cnn, gam, out);
}

// Round 2
// 281.731 us; speedup vs baseline: 2.9822x; 2.9822x over previous
//
#include <hip/hip_runtime.h>
#include <hip/hip_bf16.h>

#define BSZ 4
#define CC 64
#define NN 4096
#define CN (CC*NN)        // 262144
#define BCN (BSZ*CN)      // 1048576

typedef __attribute__((ext_vector_type(4))) float f4v;
typedef __attribute__((ext_vector_type(4))) int   i4v;
typedef __attribute__((ext_vector_type(8))) short s8v;

// DPP cross-lane (VALU pipe, not LDS): quad_perm & row rotations within 16-lane rows
#define DPP_F(x_, ctrl_) __builtin_bit_cast(float, \
    __builtin_amdgcn_update_dpp(0, __builtin_bit_cast(int, (float)(x_)), (ctrl_), 0xf, 0xf, true))
#define QP_X1 0xB1   // quad_perm [1,0,3,2]
#define QP_X2 0x4E   // quad_perm [2,3,0,1]
#define ROR4  0x124
#define ROR8  0x128

// ---------------------------------------------------------------------------
// K1: gram partials. grid 256 = (i2:2, b:4, chunk:32). Each block: 64x64 outer
// product accumulated over a 128-wide n-chunk, X staged transposed in LDS.
__global__ __launch_bounds__(256) void gram_k(const float* __restrict__ cnn,
                                              const float* __restrict__ vit,
                                              float* __restrict__ part) {
    __shared__ __align__(16) float sXT[128*68];       // [n][c], pitch 68
    int t = threadIdx.x;
    int blk = blockIdx.x;
    int ch = blk & 31, b = (blk >> 5) & 3, i2 = blk >> 7;
    const float* X = (i2 ? vit : cnn) + b * CN;
    int n0 = ch * 128;
#pragma unroll
    for (int j = 0; j < 8; j++) {
        int idx = t + j * 256;                        // 0..2047
        int c = idx >> 5, n4 = idx & 31;
        f4v val = *(const f4v*)&X[c * NN + n0 + n4 * 4];
        int base = (n4 * 4) * 68 + c;
        sXT[base]       = val[0];
        sXT[base + 68]  = val[1];
        sXT[base + 136] = val[2];
        sXT[base + 204] = val[3];
    }
    __syncthreads();
    int tc = (t & 15) * 4, td = (t >> 4) * 4;
    f4v acc[4];
#pragma unroll
    for (int i = 0; i < 4; i++) acc[i] = (f4v){0.f, 0.f, 0.f, 0.f};
    for (int k = 0; k < 128; k++) {
        f4v a  = *(const f4v*)&sXT[k * 68 + tc];
        f4v bb = *(const f4v*)&sXT[k * 68 + td];
#pragma unroll
        for (int i = 0; i < 4; i++) acc[i] += a[i] * bb;
    }
    float* dst = part + ch * 32768 + (i2 * 4 + b) * 4096;
#pragma unroll
    for (int i = 0; i < 4; i++) *(f4v*)&dst[(tc + i) * 64 + td] = acc[i];
}

// ---------------------------------------------------------------------------
// K2: reduce 32 gram partials + fused channel softmax (exp(min-x)/sum form).
__global__ void gred_k(const float* __restrict__ part, float* __restrict__ G) {
    int row = blockIdx.x;                             // 512 = 2*B*C
    int d = threadIdx.x;                              // 64
    float s = 0.f;
#pragma unroll 8
    for (int ch = 0; ch < 32; ch++) s += part[ch * 32768 + row * 64 + d];
    float mn = s;
#pragma unroll
    for (int off = 1; off < 64; off <<= 1) mn = fminf(mn, __shfl_xor(mn, off));
    float e = __expf(mn - s);
    float sm = e;
#pragma unroll
    for (int off = 1; off < 64; off <<= 1) sm += __shfl_xor(sm, off);
    G[row * 64 + d] = e / sm;
}

// ---------------------------------------------------------------------------
// K3: att[i2][b][c][n] = g_i2 * sum_d A[c,d]*X[d,n] + X[c,n]
__global__ __launch_bounds__(256) void capply_k(const float* __restrict__ cnn,
                                                const float* __restrict__ vit,
                                                const float* __restrict__ G,
                                                const float* __restrict__ gcnn,
                                                const float* __restrict__ gvit,
                                                float* __restrict__ att) {
    int idx = blockIdx.x * 256 + threadIdx.x;          // 2*B*C*N = 2^21
    int n  = idx & (NN - 1);
    int c  = (idx >> 12) & 63;
    int b  = (idx >> 18) & 3;
    int i2 = idx >> 20;
    const float* X = (i2 ? vit : cnn) + b * CN;
    const float* A = G + (i2 * 4 + b) * 4096 + c * 64;
    float s = 0.f;
#pragma unroll 8
    for (int d = 0; d < 64; d++) s += A[d] * X[d * NN + n];
    float g = i2 ? *gvit : *gcnn;
    att[idx] = g * s + X[c * NN + n];
}

// ---------------------------------------------------------------------------
// K4: fused QKV projections -> bf16 q[b][n][8], k[b][n][8], vT[b][c][n].
__global__ __launch_bounds__(256) void qkv_k(const float* __restrict__ att,
                                             const float* __restrict__ Wq, const float* __restrict__ bq,
                                             const float* __restrict__ Wk, const float* __restrict__ bk,
                                             const float* __restrict__ Wv, const float* __restrict__ bv,
                                             ushort* __restrict__ qb, ushort* __restrict__ kb,
                                             ushort* __restrict__ vT) {
    __shared__ float sWq[512], sWk[512], sWv[4096], sbq[8], sbk[8], sbv[64];
    int t = threadIdx.x;
    for (int i = t; i < 512; i += 256) { sWq[i] = Wq[i]; sWk[i] = Wk[i]; }
    for (int i = t; i < 4096; i += 256) sWv[i] = Wv[i];
    if (t < 8) { sbq[t] = bq[t]; sbk[t] = bk[t]; }
    if (t < 64) sbv[t] = bv[t];
    __syncthreads();

    int gid = blockIdx.x * 256 + t;                    // B*N = 16384
    int n = gid & (NN - 1);
    int b = gid >> 12;
    const float* xc = att + b * CN + n;                // cnn_att
    const float* xv = att + BCN + b * CN + n;          // vit_att

    float aq[8], ak[8], av[64];
#pragma unroll
    for (int o = 0; o < 8; o++) { aq[o] = sbq[o]; ak[o] = sbk[o]; }
#pragma unroll
    for (int j = 0; j < 64; j++) av[j] = sbv[j];

    for (int c = 0; c < 64; c++) {
        float a = xc[c * NN];
        float w = xv[c * NN];
#pragma unroll
        for (int o = 0; o < 8; o++) { aq[o] += a * sWq[o * 64 + c]; ak[o] += w * sWk[o * 64 + c]; }
#pragma unroll
        for (int j = 0; j < 64; j++) av[j] += w * sWv[j * 64 + c];
    }
    // pack q,k to bf16 (truncate) and store as one b128 each
    i4v pq, pk;
#pragma unroll
    for (int i = 0; i < 4; i++) {
        unsigned lo = __builtin_bit_cast(unsigned, aq[2 * i]);
        unsigned hi = __builtin_bit_cast(unsigned, aq[2 * i + 1]);
        pq[i] = (int)((hi & 0xFFFF0000u) | (lo >> 16));
        lo = __builtin_bit_cast(unsigned, ak[2 * i]);
        hi = __builtin_bit_cast(unsigned, ak[2 * i + 1]);
        pk[i] = (int)((hi & 0xFFFF0000u) | (lo >> 16));
    }
    *(i4v*)&qb[(size_t)gid * 8] = pq;
    *(i4v*)&kb[(size_t)gid * 8] = pk;

    // vT[b][c][n] bf16: pair-pack across adjacent lanes (n, n+1), even lanes store
    int lane = t & 63;
#pragma unroll
    for (int c = 0; c < 64; c++) {
        float other = __shfl_xor(av[c], 1);
        if (!(lane & 1)) {
            unsigned lo = __builtin_bit_cast(unsigned, av[c]);
            unsigned hi = __builtin_bit_cast(unsigned, other);
            unsigned pkd = (hi & 0xFFFF0000u) | (lo >> 16);
            *(unsigned*)&vT[(size_t)(b * 64 + c) * NN + n] = pkd;
        }
    }
}

// ---------------------------------------------------------------------------
// K5: MFMA flash attention + fused transpose epilogue.
// grid 256 = b(4) x qchunk(64). Block: 4 waves, wave w owns q rows q0+w*16+..15.
// QK^T: mfma 16x16x32_bf16, kdim 8 real + 24 zero-padded (A zeros kill B junk).
// P: LDS round-trip per wave (C-layout -> A-layout), pitch 72 bf16.
// V: staged transposed Vt[c][k] bf16 pitch 72; l via mfma against all-ones B.
__global__ __launch_bounds__(256) void flash_k(const ushort* __restrict__ qb,
                                               const ushort* __restrict__ kb,
                                               const ushort* __restrict__ vT,
                                               const float* __restrict__ cnn,
                                               const float* __restrict__ gamma,
                                               float* __restrict__ out) {
    __shared__ __align__(16) unsigned smem[4608];      // Vt 64*36 | P 4*16*36 (18432 B)
    unsigned* VtU = smem;                              // [c][36 words]
    unsigned* PwA = smem + 2304;

    int t = threadIdx.x;
    int lane = t & 63, w = t >> 6;
    int q4 = lane >> 4, c15 = lane & 15;
    int b = blockIdx.x >> 6;
    int q0 = (blockIdx.x & 63) * 64;
    unsigned* Pw = PwA + w * (16 * 36);

    // Q A-fragment: real kdim 0..7, zeros elsewhere
    i4v qa = (i4v){0, 0, 0, 0};
    if (q4 == 0)
        qa = *(const i4v*)(qb + (size_t)(b * NN + q0 + w * 16 + c15) * 8);
    s8v aq = __builtin_bit_cast(s8v, qa);

    i4v onesi; onesi[0] = onesi[1] = onesi[2] = onesi[3] = 0x3F803F80;  // bf16 1.0 pairs
    s8v ones = __builtin_bit_cast(s8v, onesi);

    f4v accO[4];
#pragma unroll
    for (int nt = 0; nt < 4; nt++) accO[nt] = (f4v){0.f, 0.f, 0.f, 0.f};
    f4v accl = (f4v){0.f, 0.f, 0.f, 0.f};
    float m_[4] = {-1e30f, -1e30f, -1e30f, -1e30f};

    const ushort* vTb = vT + (size_t)b * 64 * NN;
    const ushort* kbb = kb + (size_t)b * NN * 8;
    int sc = t >> 2, sk = (t & 3) * 16;

    for (int kt = 0; kt < 64; kt++) {
        int k0 = kt * 64;
        // global prefetch (regs) — overlaps with barrier drain
        i4v v0 = *(const i4v*)(vTb + (size_t)sc * NN + k0 + sk);
        i4v v1 = *(const i4v*)(vTb + (size_t)sc * NN + k0 + sk + 8);
        i4v bkf[4];
#pragma unroll
        for (int nt = 0; nt < 4; nt++)
            bkf[nt] = *(const i4v*)(kbb + (size_t)(k0 + nt * 16 + c15) * 8);

        __syncthreads();                               // prev-iter Vt reads done
        *(i4v*)&VtU[sc * 36 + (t & 3) * 8]     = v0;
        *(i4v*)&VtU[sc * 36 + (t & 3) * 8 + 4] = v1;

        // S = Q*K^T  (rows m=q, cols n=k)
        f4v z = (f4v){0.f, 0.f, 0.f, 0.f};
        f4v sS[4];
#pragma unroll
        for (int nt = 0; nt < 4; nt++)
            sS[nt] = __builtin_amdgcn_mfma_f32_16x16x32_bf16(
                aq, __builtin_bit_cast(s8v, bkf[nt]), z, 0, 0, 0);

        // online softmax: row max via in-lane + DPP over the 16-lane group
        float al[4];
#pragma unroll
        for (int r = 0; r < 4; r++) {
            float mx = fmaxf(fmaxf(sS[0][r], sS[1][r]), fmaxf(sS[2][r], sS[3][r]));
            mx = fmaxf(mx, DPP_F(mx, QP_X1));
            mx = fmaxf(mx, DPP_F(mx, QP_X2));
            mx = fmaxf(mx, DPP_F(mx, ROR4));
            mx = fmaxf(mx, DPP_F(mx, ROR8));
            float mnew = fmaxf(m_[r], mx);
            al[r] = __expf(m_[r] - mnew);
            m_[r] = mnew;
        }
        // P = exp(S - m), pack pairs via DPP, write to per-wave LDS (A-layout src)
#pragma unroll
        for (int r = 0; r < 4; r++) {
#pragma unroll
            for (int nt = 0; nt < 4; nt++) {
                float p = __expf(sS[nt][r] - m_[r]);
                float o = DPP_F(p, QP_X1);
                unsigned own = __builtin_bit_cast(unsigned, p);
                unsigned ob  = __builtin_bit_cast(unsigned, o);
                unsigned pkd = (lane & 1) ? ((own & 0xFFFF0000u) | (ob >> 16))
                                          : ((ob & 0xFFFF0000u) | (own >> 16));
                Pw[(q4 * 4 + r) * 36 + nt * 8 + (c15 >> 1)] = pkd;
            }
            accO[0][r] *= al[r]; accO[1][r] *= al[r];
            accO[2][r] *= al[r]; accO[3][r] *= al[r];
            accl[r] *= al[r];
        }
        __syncthreads();                               // Vt visible to all waves

        // PV + rowsum mfmas
        i4v pa0 = *(i4v*)&Pw[c15 * 36 + q4 * 4];
        i4v pa1 = *(i4v*)&Pw[c15 * 36 + 16 + q4 * 4];
        s8v A0 = __builtin_bit_cast(s8v, pa0);
        s8v A1 = __builtin_bit_cast(s8v, pa1);
        accl = __builtin_amdgcn_mfma_f32_16x16x32_bf16(A0, ones, accl, 0, 0, 0);
        accl = __builtin_amdgcn_mfma_f32_16x16x32_bf16(A1, ones, accl, 0, 0, 0);
#pragma unroll
        for (int nt = 0; nt < 4; nt++) {
            i4v vb0 = *(i4v*)&VtU[(nt * 16 + c15) * 36 + q4 * 4];
            i4v vb1 = *(i4v*)&VtU[(nt * 16 + c15) * 36 + 16 + q4 * 4];
            accO[nt] = __builtin_amdgcn_mfma_f32_16x16x32_bf16(
                A0, __builtin_bit_cast(s8v, vb0), accO[nt], 0, 0, 0);
            accO[nt] = __builtin_amdgcn_mfma_f32_16x16x32_bf16(
                A1, __builtin_bit_cast(s8v, vb1), accO[nt], 0, 0, 0);
        }
    }
    __syncthreads();
    // fused epilogue: O^T via LDS reuse, out = gamma*O^T + cnn
    float* OT = (float*)smem;                          // [64 c][68]
    float invl[4];
#pragma unroll
    for (int r = 0; r < 4; r++) invl[r] = 1.f / accl[r];
#pragma unroll
    for (int nt = 0; nt < 4; nt++)
#pragma unroll
        for (int r = 0; r < 4; r++)
            OT[(nt * 16 + c15) * 68 + w * 16 + q4 * 4 + r] = accO[nt][r] * invl[r];
    __syncthreads();
    float g = *gamma;
    int oc = t >> 2, oq = (t & 3) * 16;
#pragma unroll
    for (int i = 0; i < 4; i++) {
        f4v tv = *(f4v*)&OT[oc * 68 + oq + i * 4];
        size_t gi = (size_t)(b * 64 + oc) * NN + q0 + oq + i * 4;
        f4v cv = *(const f4v*)&cnn[gi];
        *(f4v*)&out[gi] = g * tv + cv;
    }
}

// ---------------------------------------------------------------------------
extern "C" void kernel_launch(void* const* d_in, const int* in_sizes, int n_in,
                              void* d_out, int out_size, void* d_ws, size_t ws_size,
                              hipStream_t stream) {
    const float* cnn  = (const float*)d_in[0];
    const float* vit  = (const float*)d_in[1];
    const float* Wq   = (const float*)d_in[2];
    const float* bq   = (const float*)d_in[3];
    const float* Wk   = (const float*)d_in[4];
    const float* bk   = (const float*)d_in[5];
    const float* Wv   = (const float*)d_in[6];
    const float* bv   = (const float*)d_in[7];
    const float* gam  = (const float*)d_in[8];
    const float* gcnn = (const float*)d_in[9];
    const float* gvit = (const float*)d_in[10];
    float* out = (float*)d_out;

    float* ws   = (float*)d_ws;
    float* att  = ws;                      // 2*B*C*N = 2097152 f
    float* G    = ws + 2097152;            // 32768 f
    float* part = ws + 2129920;            // 32*32768 = 1048576 f
    ushort* qb  = (ushort*)(ws + 3178496); // B*N*8 bf16 = 65536 f
    ushort* kb  = (ushort*)(ws + 3244032); // 65536 f
    ushort* vT  = (ushort*)(ws + 3309568); // B*64*N bf16 = 524288 f
                                           // total ~15.3 MB

    gram_k  <<<256,  256, 0, stream>>>(cnn, vit, part);
    gred_k  <<<512,  64,  0, stream>>>(part, G);
    capply_k<<<8192, 256, 0, stream>>>(cnn, vit, G, gcnn, gvit, att);
    qkv_k   <<<64,   256, 0, stream>>>(att, Wq, bq, Wk, bk, Wv, bv, qb, kb, vT);
    flash_k <<<256,  256, 0, stream>>>(qb, kb, vT, cnn, gam, out);
}

// Round 3
// 183.213 us; speedup vs baseline: 4.5859x; 1.5377x over previous
//
#include <hip/hip_runtime.h>
#include <hip/hip_bf16.h>

#define BSZ 4
#define CC 64
#define NN 4096
#define CN (CC*NN)        // 262144
#define BCN (BSZ*CN)      // 1048576

typedef __attribute__((ext_vector_type(4))) float f4v;
typedef __attribute__((ext_vector_type(4))) int   i4v;
typedef __attribute__((ext_vector_type(8))) short s8v;

// DPP cross-lane (VALU pipe): quad_perm & row rotations within 16-lane rows
#define DPP_F(x_, ctrl_) __builtin_bit_cast(float, \
    __builtin_amdgcn_update_dpp(0, __builtin_bit_cast(int, (float)(x_)), (ctrl_), 0xf, 0xf, true))
#define QP_X1 0xB1   // quad_perm [1,0,3,2]
#define QP_X2 0x4E   // quad_perm [2,3,0,1]
#define ROR4  0x124
#define ROR8  0x128

// ---------------------------------------------------------------------------
// K1: gram partials. grid 512 = (i2:2, b:4, chunk:64). 64-wide n-chunk per
// block, X staged transposed in LDS, 4x4 register tile per thread.
__global__ __launch_bounds__(256) void gram_k(const float* __restrict__ cnn,
                                              const float* __restrict__ vit,
                                              float* __restrict__ part) {
    __shared__ __align__(16) float sXT[64*68];        // [n][c], pitch 68
    int t = threadIdx.x;
    int blk = blockIdx.x;
    int ch = blk & 63, b = (blk >> 6) & 3, i2 = blk >> 8;
    const float* X = (i2 ? vit : cnn) + b * CN;
    int n0 = ch * 64;
#pragma unroll
    for (int j = 0; j < 4; j++) {
        int idx = t + j * 256;                        // 0..1023
        int c = idx >> 4, n4 = idx & 15;
        f4v val = *(const f4v*)&X[c * NN + n0 + n4 * 4];
        int base = (n4 * 4) * 68 + c;
        sXT[base]       = val[0];
        sXT[base + 68]  = val[1];
        sXT[base + 136] = val[2];
        sXT[base + 204] = val[3];
    }
    __syncthreads();
    int tc = (t & 15) * 4, td = (t >> 4) * 4;
    f4v acc[4];
#pragma unroll
    for (int i = 0; i < 4; i++) acc[i] = (f4v){0.f, 0.f, 0.f, 0.f};
    for (int k = 0; k < 64; k++) {
        f4v a  = *(const f4v*)&sXT[k * 68 + tc];
        f4v bb = *(const f4v*)&sXT[k * 68 + td];
#pragma unroll
        for (int i = 0; i < 4; i++) acc[i] += a[i] * bb;
    }
    float* dst = part + ch * 32768 + (i2 * 4 + b) * 4096;
#pragma unroll
    for (int i = 0; i < 4; i++) *(f4v*)&dst[(tc + i) * 64 + td] = acc[i];
}

// ---------------------------------------------------------------------------
// K2: reduce 64 gram partials + fused channel softmax (exp(min-x)/sum form).
// G[(i2*4+b)*4096 + c*64 + d] = attn[c][d]
__global__ void gred_k(const float* __restrict__ part, float* __restrict__ G) {
    int row = blockIdx.x;                             // 512 = 2*B*C
    int d = threadIdx.x;                              // 64
    float s = 0.f;
#pragma unroll 8
    for (int ch = 0; ch < 64; ch++) s += part[ch * 32768 + row * 64 + d];
    float mn = s;
#pragma unroll
    for (int off = 1; off < 64; off <<= 1) mn = fminf(mn, __shfl_xor(mn, off));
    float e = __expf(mn - s);
    float sm = e;
#pragma unroll
    for (int off = 1; off < 64; off <<= 1) sm += __shfl_xor(sm, off);
    G[row * 64 + d] = e / sm;
}

// ---------------------------------------------------------------------------
// K3: effective weights. Wq'[b] = gc*(Wq·Ac[b]) + Wq, etc. Exact fold of the
// channel-attention into the 1x1-conv weights: W·(g·A·X + X) = (g·W·A + W)·X.
// grid 16 = (b:4, quarter:4). Weff layout per b: [Wq' 512 | Wk' 512 | Wv' 4096]
__global__ __launch_bounds__(256) void weff_k(const float* __restrict__ G,
                                              const float* __restrict__ Wq,
                                              const float* __restrict__ Wk,
                                              const float* __restrict__ Wv,
                                              const float* __restrict__ gcnn,
                                              const float* __restrict__ gvit,
                                              float* __restrict__ Weff) {
    __shared__ float sGc[4096], sGv[4096];
    int t = threadIdx.x;
    int b = blockIdx.x >> 2, qt = blockIdx.x & 3;
    const float* Gc = G + b * 4096;
    const float* Gv = G + (4 + b) * 4096;
    for (int i = t; i < 4096; i += 256) { sGc[i] = Gc[i]; sGv[i] = Gv[i]; }
    __syncthreads();
    float gc = *gcnn, gv = *gvit;
#pragma unroll
    for (int j = 0; j < 5; j++) {
        int i = qt * 1280 + j * 256 + t;              // [0,5120)
        const float* Wrow; const float* Gs; float g, w0; int c;
        if (i < 512)       { int o = i >> 6; c = i & 63; Wrow = Wq + o * 64; Gs = sGc; g = gc; w0 = Wq[i]; }
        else if (i < 1024) { int ii = i - 512;  int o = ii >> 6; c = ii & 63; Wrow = Wk + o * 64; Gs = sGv; g = gv; w0 = Wk[ii]; }
        else               { int ii = i - 1024; int o = ii >> 6; c = ii & 63; Wrow = Wv + o * 64; Gs = sGv; g = gv; w0 = Wv[ii]; }
        float s = 0.f;
#pragma unroll 8
        for (int d = 0; d < 64; d++) s += Wrow[d] * Gs[d * 64 + c];  // A[d][c] = G[.. d*64+c]
        Weff[b * 5120 + i] = g * s + w0;
    }
}

// ---------------------------------------------------------------------------
// K4: QKV projections from ORIGINAL inputs using effective weights.
// grid 256 = (b:4, nchunk:64 of 64 columns). Wave roles: w0: q[8]+k[8]
// (interleaved bf16 b128 stores); w1..3: v rows [0,22)/[21,43)/[42,64)
// (overlap rows write identical values — benign).
__global__ __launch_bounds__(256) void qkv_k(const float* __restrict__ cnn,
                                             const float* __restrict__ vit,
                                             const float* __restrict__ Weff,
                                             const float* __restrict__ bq,
                                             const float* __restrict__ bk,
                                             const float* __restrict__ bv,
                                             ushort* __restrict__ qb, ushort* __restrict__ kb,
                                             ushort* __restrict__ vT) {
    __shared__ float sW[5120];
    __shared__ float sb[80];
    int t = threadIdx.x;
    int b = blockIdx.x >> 6, n0 = (blockIdx.x & 63) * 64;
    const float* We = Weff + b * 5120;
    for (int i = t; i < 5120; i += 256) sW[i] = We[i];
    if (t < 8) sb[t] = bq[t];
    else if (t < 16) sb[t] = bk[t - 8];
    else if (t < 80) sb[t] = bv[t - 16];
    __syncthreads();

    int w = t >> 6, lane = t & 63, n = n0 + lane;
    if (w == 0) {
        float aq[8], ak[8];
#pragma unroll
        for (int o = 0; o < 8; o++) { aq[o] = sb[o]; ak[o] = sb[8 + o]; }
        for (int c = 0; c < 64; c++) {
            float xc = cnn[b * CN + c * NN + n];
            float xv = vit[b * CN + c * NN + n];
#pragma unroll
            for (int o = 0; o < 8; o++) {
                aq[o] += xc * sW[o * 64 + c];
                ak[o] += xv * sW[512 + o * 64 + c];
            }
        }
        i4v pq, pk;
#pragma unroll
        for (int i = 0; i < 4; i++) {
            unsigned lo = __builtin_bit_cast(unsigned, aq[2 * i]);
            unsigned hi = __builtin_bit_cast(unsigned, aq[2 * i + 1]);
            pq[i] = (int)((hi & 0xFFFF0000u) | (lo >> 16));
            lo = __builtin_bit_cast(unsigned, ak[2 * i]);
            hi = __builtin_bit_cast(unsigned, ak[2 * i + 1]);
            pk[i] = (int)((hi & 0xFFFF0000u) | (lo >> 16));
        }
        *(i4v*)&qb[(size_t)(b * NN + n) * 8] = pq;
        *(i4v*)&kb[(size_t)(b * NN + n) * 8] = pk;
    } else {
        int j0 = (w - 1) * 21;                         // 0 / 21 / 42, 22 rows each
        float av[22];
#pragma unroll
        for (int j = 0; j < 22; j++) av[j] = sb[16 + j0 + j];
        for (int c = 0; c < 64; c++) {
            float xv = vit[b * CN + c * NN + n];
#pragma unroll
            for (int j = 0; j < 22; j++) av[j] += xv * sW[1024 + (j0 + j) * 64 + c];
        }
#pragma unroll
        for (int j = 0; j < 22; j++) {
            float other = __shfl_xor(av[j], 1);
            if (!(lane & 1)) {
                unsigned lo = __builtin_bit_cast(unsigned, av[j]);
                unsigned hi = __builtin_bit_cast(unsigned, other);
                *(unsigned*)&vT[(size_t)(b * 64 + j0 + j) * NN + n] =
                    (hi & 0xFFFF0000u) | (lo >> 16);
            }
        }
    }
}

// ---------------------------------------------------------------------------
// K5: MFMA flash attention, split-K x4, NO barriers in the k-loop.
// grid 1024 = (split:4, b:4, qchunk:64). Wave w owns 16 q rows; P is
// per-wave LDS; V/K B-frags load straight from global (L1-served).
// Partial (unnormalized accO, m, l) written for the combine kernel.
__global__ __launch_bounds__(256, 4) void flash_k(const ushort* __restrict__ qb,
                                                  const ushort* __restrict__ kb,
                                                  const ushort* __restrict__ vT,
                                                  float* __restrict__ pO,
                                                  float* __restrict__ pm,
                                                  float* __restrict__ pl) {
    __shared__ __align__(16) unsigned P[2304];         // 4 waves x 16 rows x 36 words
    int t = threadIdx.x;
    int lane = t & 63, w = t >> 6;
    int q4 = lane >> 4, c15 = lane & 15;
    int blk = blockIdx.x;
    int s = blk >> 8, b = (blk >> 6) & 3, q0 = (blk & 63) * 64;
    unsigned* Pw = P + w * 576;

    i4v qa = (i4v){0, 0, 0, 0};
    if (q4 == 0)
        qa = *(const i4v*)(qb + (size_t)(b * NN + q0 + w * 16 + c15) * 8);
    s8v aq = __builtin_bit_cast(s8v, qa);

    i4v onesi; onesi[0] = onesi[1] = onesi[2] = onesi[3] = 0x3F803F80;
    s8v ones = __builtin_bit_cast(s8v, onesi);

    f4v accO[4];
#pragma unroll
    for (int nt = 0; nt < 4; nt++) accO[nt] = (f4v){0.f, 0.f, 0.f, 0.f};
    f4v accl = (f4v){0.f, 0.f, 0.f, 0.f};
    float m_[4] = {-1e30f, -1e30f, -1e30f, -1e30f};

    const ushort* kbb = kb + (size_t)b * NN * 8;
    const ushort* vbase = vT + (size_t)b * 64 * NN + (size_t)c15 * NN + q4 * 8;

    for (int kt = s * 16; kt < s * 16 + 16; kt++) {
        int k0 = kt * 64;
        i4v bkf[4];
#pragma unroll
        for (int nt = 0; nt < 4; nt++)
            bkf[nt] = *(const i4v*)(kbb + (size_t)(k0 + nt * 16 + c15) * 8);
        i4v vb0[4], vb1[4];
#pragma unroll
        for (int nt = 0; nt < 4; nt++) {
            const ushort* vp = vbase + (size_t)nt * 16 * NN + k0;
            vb0[nt] = *(const i4v*)vp;
            vb1[nt] = *(const i4v*)(vp + 32);
        }

        f4v z = (f4v){0.f, 0.f, 0.f, 0.f};
        f4v sS[4];
#pragma unroll
        for (int nt = 0; nt < 4; nt++)
            sS[nt] = __builtin_amdgcn_mfma_f32_16x16x32_bf16(
                aq, __builtin_bit_cast(s8v, bkf[nt]), z, 0, 0, 0);

        float al[4];
#pragma unroll
        for (int r = 0; r < 4; r++) {
            float mx = fmaxf(fmaxf(sS[0][r], sS[1][r]), fmaxf(sS[2][r], sS[3][r]));
            mx = fmaxf(mx, DPP_F(mx, QP_X1));
            mx = fmaxf(mx, DPP_F(mx, QP_X2));
            mx = fmaxf(mx, DPP_F(mx, ROR4));
            mx = fmaxf(mx, DPP_F(mx, ROR8));
            float mnew = fmaxf(m_[r], mx);
            al[r] = __expf(m_[r] - mnew);
            m_[r] = mnew;
        }
#pragma unroll
        for (int r = 0; r < 4; r++) {
#pragma unroll
            for (int nt = 0; nt < 4; nt++) {
                float p = __expf(sS[nt][r] - m_[r]);
                float o = DPP_F(p, QP_X1);
                unsigned own = __builtin_bit_cast(unsigned, p);
                unsigned ob  = __builtin_bit_cast(unsigned, o);
                unsigned pkd = (lane & 1) ? ((own & 0xFFFF0000u) | (ob >> 16))
                                          : ((ob & 0xFFFF0000u) | (own >> 16));
                Pw[(q4 * 4 + r) * 36 + nt * 8 + (c15 >> 1)] = pkd;
            }
            accO[0][r] *= al[r]; accO[1][r] *= al[r];
            accO[2][r] *= al[r]; accO[3][r] *= al[r];
            accl[r] *= al[r];
        }
        // same-wave LDS round-trip; lgkmcnt ordering only, no barrier needed
        i4v pa0 = *(i4v*)&Pw[c15 * 36 + q4 * 4];
        i4v pa1 = *(i4v*)&Pw[c15 * 36 + 16 + q4 * 4];
        s8v A0 = __builtin_bit_cast(s8v, pa0);
        s8v A1 = __builtin_bit_cast(s8v, pa1);
        accl = __builtin_amdgcn_mfma_f32_16x16x32_bf16(A0, ones, accl, 0, 0, 0);
        accl = __builtin_amdgcn_mfma_f32_16x16x32_bf16(A1, ones, accl, 0, 0, 0);
#pragma unroll
        for (int nt = 0; nt < 4; nt++) {
            accO[nt] = __builtin_amdgcn_mfma_f32_16x16x32_bf16(
                A0, __builtin_bit_cast(s8v, vb0[nt]), accO[nt], 0, 0, 0);
            accO[nt] = __builtin_amdgcn_mfma_f32_16x16x32_bf16(
                A1, __builtin_bit_cast(s8v, vb1[nt]), accO[nt], 0, 0, 0);
        }
    }

    size_t rbase = (size_t)((s * 4 + b) * NN + q0 + w * 16 + q4 * 4);
#pragma unroll
    for (int nt = 0; nt < 4; nt++)
#pragma unroll
        for (int r = 0; r < 4; r++)
            pO[(rbase + r) * 64 + nt * 16 + c15] = accO[nt][r];
    if (c15 == 0) {
#pragma unroll
        for (int r = 0; r < 4; r++) {
            pm[rbase + r] = m_[r];                     // same value in all 16 lanes
            pl[rbase + r] = accl[r];
        }
    }
}

// ---------------------------------------------------------------------------
// K6: combine split-K partials + transpose epilogue: out = gamma*O^T + cnn.
// grid 256 = (b:4, qchunk:64).
__global__ __launch_bounds__(256) void comb_k(const float* __restrict__ pO,
                                              const float* __restrict__ pm,
                                              const float* __restrict__ pl,
                                              const float* __restrict__ cnn,
                                              const float* __restrict__ gamma,
                                              float* __restrict__ out) {
    __shared__ float OT[64 * 67];
    int t = threadIdx.x;
    int b = blockIdx.x >> 6, q0 = (blockIdx.x & 63) * 64;
    int ql = t >> 2, cg = t & 3, c0 = cg * 16;
    int qg = q0 + ql;
    float ms[4];
#pragma unroll
    for (int s = 0; s < 4; s++) ms[s] = pm[(size_t)(s * 4 + b) * NN + qg];
    float M = fmaxf(fmaxf(ms[0], ms[1]), fmaxf(ms[2], ms[3]));
    f4v O4[4];
#pragma unroll
    for (int i = 0; i < 4; i++) O4[i] = (f4v){0.f, 0.f, 0.f, 0.f};
    float L = 0.f;
#pragma unroll
    for (int s = 0; s < 4; s++) {
        float ww = __expf(ms[s] - M);
        L += ww * pl[(size_t)(s * 4 + b) * NN + qg];
        const float* src = pO + ((size_t)(s * 4 + b) * NN + qg) * 64 + c0;
#pragma unroll
        for (int i = 0; i < 4; i++) O4[i] += ww * *(const f4v*)(src + i * 4);
    }
    float inv = 1.f / L;
#pragma unroll
    for (int i = 0; i < 4; i++)
#pragma unroll
        for (int j = 0; j < 4; j++)
            OT[(c0 + i * 4 + j) * 67 + ql] = O4[i][j] * inv;
    __syncthreads();
    float g = *gamma;
    int oc = t >> 2, oq = (t & 3) * 16;
#pragma unroll
    for (int i = 0; i < 4; i++) {
        f4v tv;
#pragma unroll
        for (int jj = 0; jj < 4; jj++) tv[jj] = OT[oc * 67 + oq + i * 4 + jj];
        size_t gi = (size_t)(b * 64 + oc) * NN + q0 + oq + i * 4;
        f4v cv = *(const f4v*)&cnn[gi];
        *(f4v*)&out[gi] = g * tv + cv;
    }
}

// ---------------------------------------------------------------------------
extern "C" void kernel_launch(void* const* d_in, const int* in_sizes, int n_in,
                              void* d_out, int out_size, void* d_ws, size_t ws_size,
                              hipStream_t stream) {
    const float* cnn  = (const float*)d_in[0];
    const float* vit  = (const float*)d_in[1];
    const float* Wq   = (const float*)d_in[2];
    const float* bq   = (const float*)d_in[3];
    const float* Wk   = (const float*)d_in[4];
    const float* bk   = (const float*)d_in[5];
    const float* Wv   = (const float*)d_in[6];
    const float* bv   = (const float*)d_in[7];
    const float* gam  = (const float*)d_in[8];
    const float* gcnn = (const float*)d_in[9];
    const float* gvit = (const float*)d_in[10];
    float* out = (float*)d_out;

    float* ws   = (float*)d_ws;
    // pO (4 splits x 4 b x 4096 x 64 = 4,194,304 f) aliases part (first
    // 2,097,152 f) — part is fully consumed by gred_k before flash_k runs.
    float*  pO   = ws;
    float*  part = ws;
    float*  G    = ws + 4194304;           // 32768 f
    float*  Weff = ws + 4227072;           // 20480 f
    ushort* qb   = (ushort*)(ws + 4247552);// 131072 bf16
    ushort* kb   = (ushort*)(ws + 4313088);
    ushort* vT   = (ushort*)(ws + 4378624);// 1,048,576 bf16
    float*  pm   = ws + 4902912;           // 65536 f
    float*  pl   = ws + 4968448;           // 65536 f  (total ~20.1 MB)

    gram_k <<<512,  256, 0, stream>>>(cnn, vit, part);
    gred_k <<<512,  64,  0, stream>>>(part, G);
    weff_k <<<16,   256, 0, stream>>>(G, Wq, Wk, Wv, gcnn, gvit, Weff);
    qkv_k  <<<256,  256, 0, stream>>>(cnn, vit, Weff, bq, bk, bv, qb, kb, vT);
    flash_k<<<1024, 256, 0, stream>>>(qb, kb, vT, pO, pm, pl);
    comb_k <<<256,  256, 0, stream>>>(pO, pm, pl, cnn, gam, out);
}

// Round 4
// 181.591 us; speedup vs baseline: 4.6268x; 1.0089x over previous
//
#include <hip/hip_runtime.h>
#include <hip/hip_bf16.h>

#define BSZ 4
#define CC 64
#define NN 4096
#define CN (CC*NN)        // 262144
#define BCN (BSZ*CN)      // 1048576

typedef __attribute__((ext_vector_type(4))) float f4v;
typedef __attribute__((ext_vector_type(4))) int   i4v;
typedef __attribute__((ext_vector_type(8))) short s8v;

// DPP cross-lane (VALU pipe): quad_perm & row rotations within 16-lane rows
#define DPP_F(x_, ctrl_) __builtin_bit_cast(float, \
    __builtin_amdgcn_update_dpp(0, __builtin_bit_cast(int, (float)(x_)), (ctrl_), 0xf, 0xf, true))
#define QP_X1 0xB1   // quad_perm [1,0,3,2]
#define QP_X2 0x4E   // quad_perm [2,3,0,1]
#define ROR4  0x124
#define ROR8  0x128

__device__ __forceinline__ unsigned pack_bf16(float lo, float hi) {
    unsigned l = __builtin_bit_cast(unsigned, lo);
    unsigned h = __builtin_bit_cast(unsigned, hi);
    return (h & 0xFFFF0000u) | (l >> 16);
}

// ---------------------------------------------------------------------------
// K1: gram partials. grid 512 = (i2:2, b:4, chunk:64). 64-wide n-chunk per
// block, X staged transposed in LDS, 4x4 register tile per thread.
__global__ __launch_bounds__(256) void gram_k(const float* __restrict__ cnn,
                                              const float* __restrict__ vit,
                                              float* __restrict__ part) {
    __shared__ __align__(16) float sXT[64*68];        // [n][c], pitch 68
    int t = threadIdx.x;
    int blk = blockIdx.x;
    int ch = blk & 63, b = (blk >> 6) & 3, i2 = blk >> 8;
    const float* X = (i2 ? vit : cnn) + b * CN;
    int n0 = ch * 64;
#pragma unroll
    for (int j = 0; j < 4; j++) {
        int idx = t + j * 256;                        // 0..1023
        int c = idx >> 4, n4 = idx & 15;
        f4v val = *(const f4v*)&X[c * NN + n0 + n4 * 4];
        int base = (n4 * 4) * 68 + c;
        sXT[base]       = val[0];
        sXT[base + 68]  = val[1];
        sXT[base + 136] = val[2];
        sXT[base + 204] = val[3];
    }
    __syncthreads();
    int tc = (t & 15) * 4, td = (t >> 4) * 4;
    f4v acc[4];
#pragma unroll
    for (int i = 0; i < 4; i++) acc[i] = (f4v){0.f, 0.f, 0.f, 0.f};
    for (int k = 0; k < 64; k++) {
        f4v a  = *(const f4v*)&sXT[k * 68 + tc];
        f4v bb = *(const f4v*)&sXT[k * 68 + td];
#pragma unroll
        for (int i = 0; i < 4; i++) acc[i] += a[i] * bb;
    }
    float* dst = part + ch * 32768 + (i2 * 4 + b) * 4096;
#pragma unroll
    for (int i = 0; i < 4; i++) *(f4v*)&dst[(tc + i) * 64 + td] = acc[i];
}

// ---------------------------------------------------------------------------
// K2: reduce 64 gram partials + fused channel softmax (exp(min-x)/sum form).
// G[(i2*4+b)*4096 + c*64 + d] = A[c][d]
__global__ void gred_k(const float* __restrict__ part, float* __restrict__ G) {
    int row = blockIdx.x;                             // 512 = 2*B*C
    int d = threadIdx.x;                              // 64
    float s = 0.f;
#pragma unroll 8
    for (int ch = 0; ch < 64; ch++) s += part[ch * 32768 + row * 64 + d];
    float mn = s;
#pragma unroll
    for (int off = 1; off < 64; off <<= 1) mn = fminf(mn, __shfl_xor(mn, off));
    float e = __expf(mn - s);
    float sm = e;
#pragma unroll
    for (int off = 1; off < 64; off <<= 1) sm += __shfl_xor(sm, off);
    G[row * 64 + d] = e / sm;
}

// ---------------------------------------------------------------------------
// K3: effective weights + bf16 MFMA-A-fragment pack.
// Weff = g*(W·A) + W  (exact fold of channel attention into 1x1-conv).
// Output layout: WeffB[b][tf 0..9][lane 0..63][j 0..7] bf16, where
// tf = tile*2+frag; tile0 rows = [Wq'(8); Wk'(8)], tiles1..4 rows = Wv';
// A-frag: lane holds row m=lane&15, cols c = frag*32 + (lane>>4)*8 + j.
__global__ __launch_bounds__(256) void weff_k(const float* __restrict__ G,
                                              const float* __restrict__ Wq,
                                              const float* __restrict__ Wk,
                                              const float* __restrict__ Wv,
                                              const float* __restrict__ gcnn,
                                              const float* __restrict__ gvit,
                                              ushort* __restrict__ WeffB) {
    __shared__ float sG[8192];                        // [i2][d][c] = A[d][c]
    __shared__ float sW[5120];                        // Wq' | Wk' | Wv' fp32
    int t = threadIdx.x, b = blockIdx.x;
    for (int i = t; i < 4096; i += 256) {
        sG[i] = G[b * 4096 + i];
        sG[4096 + i] = G[(4 + b) * 4096 + i];
    }
    __syncthreads();
    float gc = *gcnn, gv = *gvit;
#pragma unroll
    for (int j = 0; j < 20; j++) {
        int i = j * 256 + t;                          // 0..5119
        const float* W; const float* A; float g; int o, c;
        if (i < 512)       { o = i >> 6; c = i & 63; W = Wq; A = sG; g = gc; }
        else if (i < 1024) { int ii = i - 512;  o = ii >> 6; c = ii & 63; W = Wk; A = sG + 4096; g = gv; }
        else               { int ii = i - 1024; o = ii >> 6; c = ii & 63; W = Wv; A = sG + 4096; g = gv; }
        float s = 0.f;
#pragma unroll 8
        for (int d = 0; d < 64; d++) s += W[o * 64 + d] * A[d * 64 + c];
        sW[i] = g * s + W[o * 64 + c];
    }
    __syncthreads();
    int lane = t & 63, m = lane & 15, q4 = lane >> 4;
    for (int tf = t >> 6; tf < 10; tf += 4) {
        int tile = tf >> 1, frag = tf & 1;
        int base = (tile == 0) ? ((m < 8) ? m * 64 : 512 + (m - 8) * 64)
                               : 1024 + ((tile - 1) * 16 + m) * 64;
        i4v out;
#pragma unroll
        for (int p = 0; p < 4; p++) {
            int c0 = frag * 32 + q4 * 8 + p * 2;
            out[p] = (int)pack_bf16(sW[base + c0], sW[base + c0 + 1]);
        }
        *(i4v*)&WeffB[(size_t)(b * 10 + tf) * 512 + lane * 8] = out;
    }
}

// ---------------------------------------------------------------------------
// K4: MFMA QKV projections. grid 256 = (b:4, nchunk:64). Wave w owns n-subtile
// n0+w*16. A-frags = WeffB (bf16, prepacked); B-frags = input columns loaded
// direct from global and packed in-register. 12 mfma per wave, no LDS.
__global__ __launch_bounds__(256) void qkv_k(const float* __restrict__ cnn,
                                             const float* __restrict__ vit,
                                             const ushort* __restrict__ WeffB,
                                             const float* __restrict__ bq,
                                             const float* __restrict__ bk,
                                             const float* __restrict__ bv,
                                             ushort* __restrict__ qb, ushort* __restrict__ kb,
                                             ushort* __restrict__ vT) {
    int t = threadIdx.x;
    int b = blockIdx.x >> 6, n0 = (blockIdx.x & 63) * 64;
    int w = t >> 6, lane = t & 63, c15 = lane & 15, q4 = lane >> 4;
    int n = n0 + w * 16 + c15;

    // A-frags (10 b128)
    s8v A[10];
    const ushort* WB = WeffB + (size_t)b * 5120 + lane * 8;
#pragma unroll
    for (int i = 0; i < 10; i++)
        A[i] = __builtin_bit_cast(s8v, *(const i4v*)(WB + (size_t)i * 512));

    // B-frags: lane holds n (col), k-slots c = f*32 + q4*8 + j
    s8v Bc[2], Bv[2];
#pragma unroll
    for (int f = 0; f < 2; f++) {
        i4v pc, pv;
#pragma unroll
        for (int p = 0; p < 4; p++) {
            int c0 = f * 32 + q4 * 8 + p * 2;
            size_t a0 = (size_t)b * CN + (size_t)c0 * NN + n;
            pc[p] = (int)pack_bf16(cnn[a0], cnn[a0 + NN]);
            pv[p] = (int)pack_bf16(vit[a0], vit[a0 + NN]);
        }
        Bc[f] = __builtin_bit_cast(s8v, pc);
        Bv[f] = __builtin_bit_cast(s8v, pv);
    }

    // job0: q rows (tile0 x cnn); valid C rows 0..7 (q4<2)
    f4v acc = *(const f4v*)(bq + (q4 & 1) * 4);
    acc = __builtin_amdgcn_mfma_f32_16x16x32_bf16(A[0], Bc[0], acc, 0, 0, 0);
    acc = __builtin_amdgcn_mfma_f32_16x16x32_bf16(A[1], Bc[1], acc, 0, 0, 0);
    if (q4 < 2) {
        unsigned d0 = pack_bf16(acc[0], acc[1]), d1 = pack_bf16(acc[2], acc[3]);
        unsigned long long v = ((unsigned long long)d1 << 32) | d0;
        *(unsigned long long*)&qb[(size_t)(b * NN + n) * 8 + q4 * 4] = v;
    }
    // job1: k rows (tile0 x vit); valid C rows 8..15 (q4>=2)
    acc = *(const f4v*)(bk + (q4 & 1) * 4);
    acc = __builtin_amdgcn_mfma_f32_16x16x32_bf16(A[0], Bv[0], acc, 0, 0, 0);
    acc = __builtin_amdgcn_mfma_f32_16x16x32_bf16(A[1], Bv[1], acc, 0, 0, 0);
    if (q4 >= 2) {
        unsigned d0 = pack_bf16(acc[0], acc[1]), d1 = pack_bf16(acc[2], acc[3]);
        unsigned long long v = ((unsigned long long)d1 << 32) | d0;
        *(unsigned long long*)&kb[(size_t)(b * NN + n) * 8 + (q4 - 2) * 4] = v;
    }
    // jobs 2..5: v rows
#pragma unroll
    for (int tile = 1; tile < 5; tile++) {
        acc = *(const f4v*)(bv + (tile - 1) * 16 + q4 * 4);
        acc = __builtin_amdgcn_mfma_f32_16x16x32_bf16(A[tile * 2],     Bv[0], acc, 0, 0, 0);
        acc = __builtin_amdgcn_mfma_f32_16x16x32_bf16(A[tile * 2 + 1], Bv[1], acc, 0, 0, 0);
#pragma unroll
        for (int r = 0; r < 4; r++) {
            float other = DPP_F(acc[r], QP_X1);
            unsigned pkd = (lane & 1) ? pack_bf16(other, acc[r])
                                      : pack_bf16(acc[r], other);
            if (!(lane & 1)) {
                int row = (tile - 1) * 16 + q4 * 4 + r;
                *(unsigned*)&vT[(size_t)(b * 64 + row) * NN + n] = pkd;
            }
        }
    }
}

// ---------------------------------------------------------------------------
// K5: MFMA flash attention, split-K x4, barrier-free. grid 512 =
// (split:4, b:4, qchunk:32 of 128 rows). Wave w owns 32 q rows (2 groups of
// 16 sharing the K/V B-frags). P: per-wave LDS round-trip (C->A layout).
__global__ __launch_bounds__(256) void flash_k(const ushort* __restrict__ qb,
                                               const ushort* __restrict__ kb,
                                               const ushort* __restrict__ vT,
                                               float* __restrict__ pO,
                                               float* __restrict__ pm,
                                               float* __restrict__ pl) {
    __shared__ __align__(16) unsigned P[4608];         // 4 waves x 32 rows x 36
    int t = threadIdx.x;
    int lane = t & 63, w = t >> 6;
    int c15 = lane & 15, q4 = lane >> 4;
    int blk = blockIdx.x;
    int s = blk >> 7, b = (blk >> 5) & 3, q0 = (blk & 31) * 128;
    unsigned* Pw = P + w * 1152;

    s8v aq[2];
#pragma unroll
    for (int g = 0; g < 2; g++) {
        i4v qa = (i4v){0, 0, 0, 0};
        if (q4 == 0)
            qa = *(const i4v*)(qb + (size_t)(b * NN + q0 + w * 32 + g * 16 + c15) * 8);
        aq[g] = __builtin_bit_cast(s8v, qa);
    }
    i4v onesi; onesi[0] = onesi[1] = onesi[2] = onesi[3] = 0x3F803F80;
    s8v ones = __builtin_bit_cast(s8v, onesi);

    f4v accO[2][4];
#pragma unroll
    for (int g = 0; g < 2; g++)
#pragma unroll
        for (int nt = 0; nt < 4; nt++) accO[g][nt] = (f4v){0.f, 0.f, 0.f, 0.f};
    f4v accl[2] = {(f4v){0.f,0.f,0.f,0.f}, (f4v){0.f,0.f,0.f,0.f}};
    float m_[2][4] = {{-1e30f,-1e30f,-1e30f,-1e30f},{-1e30f,-1e30f,-1e30f,-1e30f}};

    const ushort* kbb = kb + (size_t)b * NN * 8;
    const ushort* vbase = vT + (size_t)b * 64 * NN + (size_t)c15 * NN + q4 * 8;

    for (int kt = s * 16; kt < s * 16 + 16; kt++) {
        int k0 = kt * 64;
        i4v bkf[4];
#pragma unroll
        for (int nt = 0; nt < 4; nt++)
            bkf[nt] = *(const i4v*)(kbb + (size_t)(k0 + nt * 16 + c15) * 8);
        i4v vb0[4], vb1[4];
#pragma unroll
        for (int nt = 0; nt < 4; nt++) {
            const ushort* vp = vbase + (size_t)nt * 16 * NN + k0;
            vb0[nt] = *(const i4v*)vp;
            vb1[nt] = *(const i4v*)(vp + 32);
        }

        f4v z = (f4v){0.f, 0.f, 0.f, 0.f};
        f4v S[2][4];
#pragma unroll
        for (int g = 0; g < 2; g++)
#pragma unroll
            for (int nt = 0; nt < 4; nt++)
                S[g][nt] = __builtin_amdgcn_mfma_f32_16x16x32_bf16(
                    aq[g], __builtin_bit_cast(s8v, bkf[nt]), z, 0, 0, 0);

        float al[2][4];
#pragma unroll
        for (int g = 0; g < 2; g++)
#pragma unroll
            for (int r = 0; r < 4; r++) {
                float mx = fmaxf(fmaxf(S[g][0][r], S[g][1][r]),
                                 fmaxf(S[g][2][r], S[g][3][r]));
                mx = fmaxf(mx, DPP_F(mx, QP_X1));
                mx = fmaxf(mx, DPP_F(mx, QP_X2));
                mx = fmaxf(mx, DPP_F(mx, ROR4));
                mx = fmaxf(mx, DPP_F(mx, ROR8));
                float mnew = fmaxf(m_[g][r], mx);
                al[g][r] = __expf(m_[g][r] - mnew);
                m_[g][r] = mnew;
            }
#pragma unroll
        for (int g = 0; g < 2; g++)
#pragma unroll
            for (int r = 0; r < 4; r++) {
#pragma unroll
                for (int nt = 0; nt < 4; nt++) {
                    float p = __expf(S[g][nt][r] - m_[g][r]);
                    float o = DPP_F(p, QP_X1);
                    unsigned pkd = (lane & 1) ? pack_bf16(o, p) : pack_bf16(p, o);
                    Pw[(g * 16 + q4 * 4 + r) * 36 + nt * 8 + (c15 >> 1)] = pkd;
                }
                float a = al[g][r];
                accO[g][0][r] *= a; accO[g][1][r] *= a;
                accO[g][2][r] *= a; accO[g][3][r] *= a;
                accl[g][r] *= a;
            }
        // same-wave LDS round-trip (lgkmcnt ordering only, no barrier)
#pragma unroll
        for (int g = 0; g < 2; g++) {
            i4v pa0 = *(i4v*)&Pw[(g * 16 + c15) * 36 + q4 * 4];
            i4v pa1 = *(i4v*)&Pw[(g * 16 + c15) * 36 + 16 + q4 * 4];
            s8v A0 = __builtin_bit_cast(s8v, pa0);
            s8v A1 = __builtin_bit_cast(s8v, pa1);
            accl[g] = __builtin_amdgcn_mfma_f32_16x16x32_bf16(A0, ones, accl[g], 0, 0, 0);
            accl[g] = __builtin_amdgcn_mfma_f32_16x16x32_bf16(A1, ones, accl[g], 0, 0, 0);
#pragma unroll
            for (int nt = 0; nt < 4; nt++) {
                accO[g][nt] = __builtin_amdgcn_mfma_f32_16x16x32_bf16(
                    A0, __builtin_bit_cast(s8v, vb0[nt]), accO[g][nt], 0, 0, 0);
                accO[g][nt] = __builtin_amdgcn_mfma_f32_16x16x32_bf16(
                    A1, __builtin_bit_cast(s8v, vb1[nt]), accO[g][nt], 0, 0, 0);
            }
        }
    }

#pragma unroll
    for (int g = 0; g < 2; g++) {
        size_t rbase = (size_t)((s * 4 + b) * NN + q0 + w * 32 + g * 16 + q4 * 4);
#pragma unroll
        for (int nt = 0; nt < 4; nt++)
#pragma unroll
            for (int r = 0; r < 4; r++)
                pO[(rbase + r) * 64 + nt * 16 + c15] = accO[g][nt][r];
        if (c15 == 0) {
#pragma unroll
            for (int r = 0; r < 4; r++) {
                pm[rbase + r] = m_[g][r];
                pl[rbase + r] = accl[g][r];
            }
        }
    }
}

// ---------------------------------------------------------------------------
// K6: combine split-K partials + transpose epilogue: out = gamma*O^T + cnn.
// grid 256 = (b:4, qchunk:64).
__global__ __launch_bounds__(256) void comb_k(const float* __restrict__ pO,
                                              const float* __restrict__ pm,
                                              const float* __restrict__ pl,
                                              const float* __restrict__ cnn,
                                              const float* __restrict__ gamma,
                                              float* __restrict__ out) {
    __shared__ float OT[64 * 67];
    int t = threadIdx.x;
    int b = blockIdx.x >> 6, q0 = (blockIdx.x & 63) * 64;
    int ql = t >> 2, cg = t & 3, c0 = cg * 16;
    int qg = q0 + ql;
    float ms[4];
#pragma unroll
    for (int s = 0; s < 4; s++) ms[s] = pm[(size_t)(s * 4 + b) * NN + qg];
    float M = fmaxf(fmaxf(ms[0], ms[1]), fmaxf(ms[2], ms[3]));
    f4v O4[4];
#pragma unroll
    for (int i = 0; i < 4; i++) O4[i] = (f4v){0.f, 0.f, 0.f, 0.f};
    float L = 0.f;
#pragma unroll
    for (int s = 0; s < 4; s++) {
        float ww = __expf(ms[s] - M);
        L += ww * pl[(size_t)(s * 4 + b) * NN + qg];
        const float* src = pO + ((size_t)(s * 4 + b) * NN + qg) * 64 + c0;
#pragma unroll
        for (int i = 0; i < 4; i++) O4[i] += ww * *(const f4v*)(src + i * 4);
    }
    float inv = 1.f / L;
#pragma unroll
    for (int i = 0; i < 4; i++)
#pragma unroll
        for (int j = 0; j < 4; j++)
            OT[(c0 + i * 4 + j) * 67 + ql] = O4[i][j] * inv;
    __syncthreads();
    float g = *gamma;
    int oc = t >> 2, oq = (t & 3) * 16;
#pragma unroll
    for (int i = 0; i < 4; i++) {
        f4v tv;
#pragma unroll
        for (int jj = 0; jj < 4; jj++) tv[jj] = OT[oc * 67 + oq + i * 4 + jj];
        size_t gi = (size_t)(b * 64 + oc) * NN + q0 + oq + i * 4;
        f4v cv = *(const f4v*)&cnn[gi];
        *(f4v*)&out[gi] = g * tv + cv;
    }
}

// ---------------------------------------------------------------------------
extern "C" void kernel_launch(void* const* d_in, const int* in_sizes, int n_in,
                              void* d_out, int out_size, void* d_ws, size_t ws_size,
                              hipStream_t stream) {
    const float* cnn  = (const float*)d_in[0];
    const float* vit  = (const float*)d_in[1];
    const float* Wq   = (const float*)d_in[2];
    const float* bq   = (const float*)d_in[3];
    const float* Wk   = (const float*)d_in[4];
    const float* bk   = (const float*)d_in[5];
    const float* Wv   = (const float*)d_in[6];
    const float* bv   = (const float*)d_in[7];
    const float* gam  = (const float*)d_in[8];
    const float* gcnn = (const float*)d_in[9];
    const float* gvit = (const float*)d_in[10];
    float* out = (float*)d_out;

    float* ws = (float*)d_ws;
    // pO (16 MB) aliases part (first 8 MB) — part fully consumed by gred_k
    // before flash_k writes pO.
    float*  pO    = ws;
    float*  part  = ws;
    float*  G     = ws + 4194304;            // 32768 f
    ushort* WeffB = (ushort*)(ws + 4227072); // 20480 bf16 (10240 f)
    ushort* qb    = (ushort*)(ws + 4237312); // 131072 bf16
    ushort* kb    = (ushort*)(ws + 4302848);
    ushort* vT    = (ushort*)(ws + 4368384); // 1048576 bf16
    float*  pm    = ws + 4892672;            // 65536 f
    float*  pl    = ws + 4958208;            // 65536 f  (total ~20.1 MB)

    gram_k <<<512, 256, 0, stream>>>(cnn, vit, part);
    gred_k <<<512, 64,  0, stream>>>(part, G);
    weff_k <<<4,   256, 0, stream>>>(G, Wq, Wk, Wv, gcnn, gvit, WeffB);
    qkv_k  <<<256, 256, 0, stream>>>(cnn, vit, WeffB, bq, bk, bv, qb, kb, vT);
    flash_k<<<512, 256, 0, stream>>>(qb, kb, vT, pO, pm, pl);
    comb_k <<<256, 256, 0, stream>>>(pO, pm, pl, cnn, gam, out);
}

// Round 5
// 147.027 us; speedup vs baseline: 5.7145x; 1.2351x over previous
//
#include <hip/hip_runtime.h>
#include <hip/hip_bf16.h>

#define BSZ 4
#define CC 64
#define NN 4096
#define CN (CC*NN)        // 262144
#define BCN (BSZ*CN)      // 1048576

typedef __attribute__((ext_vector_type(4))) float    f4v;
typedef __attribute__((ext_vector_type(4))) int      i4v;
typedef __attribute__((ext_vector_type(2))) unsigned u2v;
typedef __attribute__((ext_vector_type(8))) short    s8v;

// DPP cross-lane (VALU pipe): quad_perm within quads
#define DPP_F(x_, ctrl_) __builtin_bit_cast(float, \
    __builtin_amdgcn_update_dpp(0, __builtin_bit_cast(int, (float)(x_)), (ctrl_), 0xf, 0xf, true))
#define QP_X1 0xB1   // quad_perm [1,0,3,2]

__device__ __forceinline__ unsigned pack_bf16(float lo, float hi) {
    unsigned l = __builtin_bit_cast(unsigned, lo);
    unsigned h = __builtin_bit_cast(unsigned, hi);
    return (h & 0xFFFF0000u) | (l >> 16);
}

// ---------------------------------------------------------------------------
// K1: gram partials. grid 512 = (i2:2, b:4, chunk:64). 64-wide n-chunk per
// block, X staged transposed in LDS, 4x4 register tile per thread.
__global__ __launch_bounds__(256) void gram_k(const float* __restrict__ cnn,
                                              const float* __restrict__ vit,
                                              float* __restrict__ part) {
    __shared__ __align__(16) float sXT[64*68];        // [n][c], pitch 68
    int t = threadIdx.x;
    int blk = blockIdx.x;
    int ch = blk & 63, b = (blk >> 6) & 3, i2 = blk >> 8;
    const float* X = (i2 ? vit : cnn) + b * CN;
    int n0 = ch * 64;
#pragma unroll
    for (int j = 0; j < 4; j++) {
        int idx = t + j * 256;                        // 0..1023
        int c = idx >> 4, n4 = idx & 15;
        f4v val = *(const f4v*)&X[c * NN + n0 + n4 * 4];
        int base = (n4 * 4) * 68 + c;
        sXT[base]       = val[0];
        sXT[base + 68]  = val[1];
        sXT[base + 136] = val[2];
        sXT[base + 204] = val[3];
    }
    __syncthreads();
    int tc = (t & 15) * 4, td = (t >> 4) * 4;
    f4v acc[4];
#pragma unroll
    for (int i = 0; i < 4; i++) acc[i] = (f4v){0.f, 0.f, 0.f, 0.f};
    for (int k = 0; k < 64; k++) {
        f4v a  = *(const f4v*)&sXT[k * 68 + tc];
        f4v bb = *(const f4v*)&sXT[k * 68 + td];
#pragma unroll
        for (int i = 0; i < 4; i++) acc[i] += a[i] * bb;
    }
    float* dst = part + ch * 32768 + (i2 * 4 + b) * 4096;
#pragma unroll
    for (int i = 0; i < 4; i++) *(f4v*)&dst[(tc + i) * 64 + td] = acc[i];
}

// ---------------------------------------------------------------------------
// K2: reduce 64 gram partials + fused channel softmax (exp(min-x)/sum form).
__global__ void gred_k(const float* __restrict__ part, float* __restrict__ G) {
    int row = blockIdx.x;                             // 512 = 2*B*C
    int d = threadIdx.x;                              // 64
    float s = 0.f;
#pragma unroll 8
    for (int ch = 0; ch < 64; ch++) s += part[ch * 32768 + row * 64 + d];
    float mn = s;
#pragma unroll
    for (int off = 1; off < 64; off <<= 1) mn = fminf(mn, __shfl_xor(mn, off));
    float e = __expf(mn - s);
    float sm = e;
#pragma unroll
    for (int off = 1; off < 64; off <<= 1) sm += __shfl_xor(sm, off);
    G[row * 64 + d] = e / sm;
}

// ---------------------------------------------------------------------------
// K3: effective weights + bf16 MFMA-A-fragment pack. grid 20 = (b:4, tile:5).
// Weff = g*(W·A) + W (exact fold). tile0 rows = [Wq'(8); Wk'(8)], tiles1..4 =
// Wv' 16-row chunks. Output per tile: 2 frags, A-frag layout
// (m=lane&15, c = frag*32 + (lane>>4)*8 + j).
__global__ __launch_bounds__(256) void weff_k(const float* __restrict__ G,
                                              const float* __restrict__ Wq,
                                              const float* __restrict__ Wk,
                                              const float* __restrict__ Wv,
                                              const float* __restrict__ gcnn,
                                              const float* __restrict__ gvit,
                                              ushort* __restrict__ WeffB) {
    __shared__ float sA[8192];                        // Gc | Gv  (A[d][c])
    __shared__ float sWt[1024];                       // this tile's 16x64 fp32
    int t = threadIdx.x;
    int b = blockIdx.x / 5, tile = blockIdx.x % 5;
    for (int i = t; i < 4096; i += 256) {
        sA[i]        = G[b * 4096 + i];
        sA[4096 + i] = G[(4 + b) * 4096 + i];
    }
    __syncthreads();
    float gc = *gcnn, gv = *gvit;
#pragma unroll
    for (int k = 0; k < 4; k++) {
        int idx = k * 256 + t;                        // 0..1023
        int r = idx >> 6, c = idx & 63;
        const float* Wrow; const float* A; float g;
        if (tile == 0) {
            if (r < 8) { Wrow = Wq + r * 64;       A = sA;        g = gc; }
            else       { Wrow = Wk + (r - 8) * 64; A = sA + 4096; g = gv; }
        } else         { Wrow = Wv + ((tile - 1) * 16 + r) * 64; A = sA + 4096; g = gv; }
        float s = 0.f;
#pragma unroll 8
        for (int d = 0; d < 64; d++) s += Wrow[d] * A[d * 64 + c];
        sWt[idx] = g * s + Wrow[c];
    }
    __syncthreads();
    if (t < 128) {
        int frag = t >> 6, lane = t & 63, m = lane & 15, q4 = lane >> 4;
        i4v o;
#pragma unroll
        for (int p = 0; p < 4; p++) {
            int c0 = frag * 32 + q4 * 8 + 2 * p;
            o[p] = (int)pack_bf16(sWt[m * 64 + c0], sWt[m * 64 + c0 + 1]);
        }
        *(i4v*)&WeffB[(size_t)(b * 10 + tile * 2 + frag) * 512 + lane * 8] = o;
    }
}

// ---------------------------------------------------------------------------
// K4: MFMA QKV projections. grid 256 = (b:4, nchunk:64). q is scaled by
// log2(e) so flash can use native v_exp_f32 (2^x) directly.
__global__ __launch_bounds__(256) void qkv_k(const float* __restrict__ cnn,
                                             const float* __restrict__ vit,
                                             const ushort* __restrict__ WeffB,
                                             const float* __restrict__ bq,
                                             const float* __restrict__ bk,
                                             const float* __restrict__ bv,
                                             ushort* __restrict__ qb, ushort* __restrict__ kb,
                                             ushort* __restrict__ vT) {
    int t = threadIdx.x;
    int b = blockIdx.x >> 6, n0 = (blockIdx.x & 63) * 64;
    int w = t >> 6, lane = t & 63, c15 = lane & 15, q4 = lane >> 4;
    int n = n0 + w * 16 + c15;
    const float LOG2E = 1.44269504f;

    s8v A[10];
    const ushort* WB = WeffB + (size_t)b * 5120 + lane * 8;
#pragma unroll
    for (int i = 0; i < 10; i++)
        A[i] = __builtin_bit_cast(s8v, *(const i4v*)(WB + (size_t)i * 512));

    s8v Bc[2], Bv[2];
#pragma unroll
    for (int f = 0; f < 2; f++) {
        i4v pc, pv;
#pragma unroll
        for (int p = 0; p < 4; p++) {
            int c0 = f * 32 + q4 * 8 + p * 2;
            size_t a0 = (size_t)b * CN + (size_t)c0 * NN + n;
            pc[p] = (int)pack_bf16(cnn[a0], cnn[a0 + NN]);
            pv[p] = (int)pack_bf16(vit[a0], vit[a0 + NN]);
        }
        Bc[f] = __builtin_bit_cast(s8v, pc);
        Bv[f] = __builtin_bit_cast(s8v, pv);
    }

    // q rows (scaled by log2e)
    f4v acc = *(const f4v*)(bq + (q4 & 1) * 4);
    acc = __builtin_amdgcn_mfma_f32_16x16x32_bf16(A[0], Bc[0], acc, 0, 0, 0);
    acc = __builtin_amdgcn_mfma_f32_16x16x32_bf16(A[1], Bc[1], acc, 0, 0, 0);
    if (q4 < 2) {
        unsigned d0 = pack_bf16(acc[0] * LOG2E, acc[1] * LOG2E);
        unsigned d1 = pack_bf16(acc[2] * LOG2E, acc[3] * LOG2E);
        unsigned long long v = ((unsigned long long)d1 << 32) | d0;
        *(unsigned long long*)&qb[(size_t)(b * NN + n) * 8 + q4 * 4] = v;
    }
    // k rows
    acc = *(const f4v*)(bk + (q4 & 1) * 4);
    acc = __builtin_amdgcn_mfma_f32_16x16x32_bf16(A[0], Bv[0], acc, 0, 0, 0);
    acc = __builtin_amdgcn_mfma_f32_16x16x32_bf16(A[1], Bv[1], acc, 0, 0, 0);
    if (q4 >= 2) {
        unsigned d0 = pack_bf16(acc[0], acc[1]), d1 = pack_bf16(acc[2], acc[3]);
        unsigned long long v = ((unsigned long long)d1 << 32) | d0;
        *(unsigned long long*)&kb[(size_t)(b * NN + n) * 8 + (q4 - 2) * 4] = v;
    }
    // v rows -> vT[b][c][n]
#pragma unroll
    for (int tile = 1; tile < 5; tile++) {
        acc = *(const f4v*)(bv + (tile - 1) * 16 + q4 * 4);
        acc = __builtin_amdgcn_mfma_f32_16x16x32_bf16(A[tile * 2],     Bv[0], acc, 0, 0, 0);
        acc = __builtin_amdgcn_mfma_f32_16x16x32_bf16(A[tile * 2 + 1], Bv[1], acc, 0, 0, 0);
#pragma unroll
        for (int r = 0; r < 4; r++) {
            float other = DPP_F(acc[r], QP_X1);
            unsigned pkd = (lane & 1) ? pack_bf16(other, acc[r])
                                      : pack_bf16(acc[r], other);
            if (!(lane & 1)) {
                int row = (tile - 1) * 16 + q4 * 4 + r;
                *(unsigned*)&vT[(size_t)(b * 64 + row) * NN + n] = pkd;
            }
        }
    }
}

// ---------------------------------------------------------------------------
// K5: operand-swapped MFMA flash attention, split-K x4, barrier-free.
// grid 512 = (split:4, b:4, qchunk:32 of 128 rows). Wave w owns 32 q
// (2 groups of 16). S^T = mfma(A=K, B=Q) puts q in lane&15: softmax state is
// per-lane scalar; P packs in-lane; PV = mfma(A=V^T, B=P) yields O^T[c][q]
// directly (no epilogue transpose). All in log2 domain (q pre-scaled).
__global__ __launch_bounds__(256, 2) void flash_k(const ushort* __restrict__ qb,
                                                  const ushort* __restrict__ kb,
                                                  const ushort* __restrict__ vT,
                                                  float* __restrict__ pOT,
                                                  float* __restrict__ pm,
                                                  float* __restrict__ pl) {
    __shared__ __align__(16) unsigned P[4608];         // 4 waves x 2 g x 16 q x 36
    int t = threadIdx.x;
    int lane = t & 63, w = t >> 6;
    int c15 = lane & 15, q4 = lane >> 4;
    int blk = blockIdx.x;
    int s = blk >> 7, b = (blk >> 5) & 3, q0 = (blk & 31) * 128;
    unsigned* Pw = P + w * 1152;

    // Q B-frags: lane&15 = q, k-slots = d (real for q4==0, zero-pad else)
    s8v qB[2];
#pragma unroll
    for (int g = 0; g < 2; g++) {
        i4v qa = (i4v){0, 0, 0, 0};
        if (q4 == 0)
            qa = *(const i4v*)(qb + (size_t)(b * NN + q0 + w * 32 + g * 16 + c15) * 8);
        qB[g] = __builtin_bit_cast(s8v, qa);
    }
    i4v onesi; onesi[0] = onesi[1] = onesi[2] = onesi[3] = 0x3F803F80;
    s8v ones = __builtin_bit_cast(s8v, onesi);

    f4v accO[2][4];
#pragma unroll
    for (int g = 0; g < 2; g++)
#pragma unroll
        for (int nt = 0; nt < 4; nt++) accO[g][nt] = (f4v){0.f, 0.f, 0.f, 0.f};
    f4v accl[2] = {(f4v){0.f,0.f,0.f,0.f}, (f4v){0.f,0.f,0.f,0.f}};
    float m_[2] = {-1e30f, -1e30f};

    const ushort* kbb = kb + (size_t)b * NN * 8;
    const ushort* vbase = vT + (size_t)b * 64 * NN + (size_t)c15 * NN + q4 * 8;

    int kt0 = s * 16;
    // preload K frags for kt0
    i4v bkf[4];
#pragma unroll
    for (int nt = 0; nt < 4; nt++)
        bkf[nt] = *(const i4v*)(kbb + (size_t)(kt0 * 64 + nt * 16 + c15) * 8);

    for (int kt = kt0; kt < kt0 + 16; kt++) {
        int k0 = kt * 64;
        // V^T A-frags for current kt (used late -> latency hidden)
        i4v vb0[4], vb1[4];
#pragma unroll
        for (int nt = 0; nt < 4; nt++) {
            const ushort* vp = vbase + (size_t)nt * 16 * NN + k0;
            vb0[nt] = *(const i4v*)vp;
            vb1[nt] = *(const i4v*)(vp + 32);
        }

        // S^T = K * Q^T : C[m=k-seq][n=q]
        f4v z = (f4v){0.f, 0.f, 0.f, 0.f};
        f4v S[2][4];
#pragma unroll
        for (int g = 0; g < 2; g++)
#pragma unroll
            for (int nt = 0; nt < 4; nt++)
                S[g][nt] = __builtin_amdgcn_mfma_f32_16x16x32_bf16(
                    __builtin_bit_cast(s8v, bkf[nt]), qB[g], z, 0, 0, 0);

        // prefetch next kt's K frags
        int ktn = (kt + 1 < kt0 + 16) ? kt + 1 : kt;
        i4v nbkf[4];
#pragma unroll
        for (int nt = 0; nt < 4; nt++)
            nbkf[nt] = *(const i4v*)(kbb + (size_t)(ktn * 64 + nt * 16 + c15) * 8);

        // online softmax (log2 domain), per-lane scalar state
        float al[2];
#pragma unroll
        for (int g = 0; g < 2; g++) {
            f4v m4 = __builtin_elementwise_max(
                __builtin_elementwise_max(S[g][0], S[g][1]),
                __builtin_elementwise_max(S[g][2], S[g][3]));
            float mx = fmaxf(fmaxf(m4[0], m4[1]), fmaxf(m4[2], m4[3]));
            mx = fmaxf(mx, __shfl_xor(mx, 16));
            mx = fmaxf(mx, __shfl_xor(mx, 32));
            float mnew = fmaxf(m_[g], mx);
            al[g] = __builtin_amdgcn_exp2f(m_[g] - mnew);
            m_[g] = mnew;
            // exp, in-lane pair pack, LDS [q][k2-dword] (pitch 36)
            unsigned* Pg = Pw + g * 576 + c15 * 36;
#pragma unroll
            for (int nt = 0; nt < 4; nt++) {
                float p0 = __builtin_amdgcn_exp2f(S[g][nt][0] - mnew);
                float p1 = __builtin_amdgcn_exp2f(S[g][nt][1] - mnew);
                float p2 = __builtin_amdgcn_exp2f(S[g][nt][2] - mnew);
                float p3 = __builtin_amdgcn_exp2f(S[g][nt][3] - mnew);
                u2v d2; d2[0] = pack_bf16(p0, p1); d2[1] = pack_bf16(p2, p3);
                *(u2v*)&Pg[nt * 8 + 2 * q4] = d2;
            }
#pragma unroll
            for (int nt = 0; nt < 4; nt++) accO[g][nt] *= al[g];
            accl[g] *= al[g];
        }

        // PV: O^T += V^T * P   (same-wave LDS round-trip, no barrier)
#pragma unroll
        for (int g = 0; g < 2; g++) {
            i4v pb0 = *(i4v*)&Pw[g * 576 + c15 * 36 + 4 * q4];
            i4v pb1 = *(i4v*)&Pw[g * 576 + c15 * 36 + 16 + 4 * q4];
            s8v B0 = __builtin_bit_cast(s8v, pb0);
            s8v B1 = __builtin_bit_cast(s8v, pb1);
            accl[g] = __builtin_amdgcn_mfma_f32_16x16x32_bf16(ones, B0, accl[g], 0, 0, 0);
            accl[g] = __builtin_amdgcn_mfma_f32_16x16x32_bf16(ones, B1, accl[g], 0, 0, 0);
#pragma unroll
            for (int nt = 0; nt < 4; nt++) {
                accO[g][nt] = __builtin_amdgcn_mfma_f32_16x16x32_bf16(
                    __builtin_bit_cast(s8v, vb0[nt]), B0, accO[g][nt], 0, 0, 0);
                accO[g][nt] = __builtin_amdgcn_mfma_f32_16x16x32_bf16(
                    __builtin_bit_cast(s8v, vb1[nt]), B1, accO[g][nt], 0, 0, 0);
            }
        }
#pragma unroll
        for (int nt = 0; nt < 4; nt++) bkf[nt] = nbkf[nt];
    }

    // store O^T partials (already [c][q]-major), m, l
#pragma unroll
    for (int g = 0; g < 2; g++) {
        int qg = q0 + w * 32 + g * 16 + c15;
#pragma unroll
        for (int nt = 0; nt < 4; nt++)
#pragma unroll
            for (int r = 0; r < 4; r++) {
                int c = nt * 16 + q4 * 4 + r;
                pOT[(size_t)((s * 4 + b) * 64 + c) * NN + qg] = accO[g][nt][r];
            }
        if (q4 == 0) {
            pm[(size_t)(s * 4 + b) * NN + qg] = m_[g];
            pl[(size_t)(s * 4 + b) * NN + qg] = accl[g][0];
        }
    }
}

// ---------------------------------------------------------------------------
// K6: combine split-K partials (transpose-free): out = gamma*O + cnn.
// grid 256 = (b:4, nchunk:64 of 64). pOT is [s][b][c][n].
__global__ __launch_bounds__(256) void comb_k(const float* __restrict__ pOT,
                                              const float* __restrict__ pm,
                                              const float* __restrict__ pl,
                                              const float* __restrict__ cnn,
                                              const float* __restrict__ gamma,
                                              float* __restrict__ out) {
    int t = threadIdx.x;
    int b = blockIdx.x >> 6, n0 = (blockIdx.x & 63) * 64;
    int nq = t & 15, cl = t >> 4;
    int n = n0 + nq * 4;
    f4v pmv[4], plv[4];
#pragma unroll
    for (int s = 0; s < 4; s++) {
        pmv[s] = *(const f4v*)&pm[(size_t)(s * 4 + b) * NN + n];
        plv[s] = *(const f4v*)&pl[(size_t)(s * 4 + b) * NN + n];
    }
    f4v M = __builtin_elementwise_max(__builtin_elementwise_max(pmv[0], pmv[1]),
                                      __builtin_elementwise_max(pmv[2], pmv[3]));
    f4v wsc[4], L = (f4v){0.f, 0.f, 0.f, 0.f};
#pragma unroll
    for (int s = 0; s < 4; s++) {
        f4v e;
#pragma unroll
        for (int j = 0; j < 4; j++) e[j] = __builtin_amdgcn_exp2f(pmv[s][j] - M[j]);
        wsc[s] = e;
        L += e * plv[s];
    }
    float g = *gamma;
    f4v rv;
#pragma unroll
    for (int j = 0; j < 4; j++) rv[j] = g / L[j];
#pragma unroll
    for (int it = 0; it < 4; it++) {
        int c = it * 16 + cl;
        f4v o = (f4v){0.f, 0.f, 0.f, 0.f};
#pragma unroll
        for (int s = 0; s < 4; s++)
            o += wsc[s] * *(const f4v*)&pOT[(size_t)((s * 4 + b) * 64 + c) * NN + n];
        size_t gi = (size_t)(b * 64 + c) * NN + n;
        f4v cv = *(const f4v*)&cnn[gi];
        *(f4v*)&out[gi] = o * rv + cv;
    }
}

// ---------------------------------------------------------------------------
extern "C" void kernel_launch(void* const* d_in, const int* in_sizes, int n_in,
                              void* d_out, int out_size, void* d_ws, size_t ws_size,
                              hipStream_t stream) {
    const float* cnn  = (const float*)d_in[0];
    const float* vit  = (const float*)d_in[1];
    const float* Wq   = (const float*)d_in[2];
    const float* bq   = (const float*)d_in[3];
    const float* Wk   = (const float*)d_in[4];
    const float* bk   = (const float*)d_in[5];
    const float* Wv   = (const float*)d_in[6];
    const float* bv   = (const float*)d_in[7];
    const float* gam  = (const float*)d_in[8];
    const float* gcnn = (const float*)d_in[9];
    const float* gvit = (const float*)d_in[10];
    float* out = (float*)d_out;

    float* ws = (float*)d_ws;
    // pOT (16 MB) aliases part (first 8 MB) — part is consumed by gred_k
    // before flash_k writes pOT.
    float*  pOT   = ws;
    float*  part  = ws;
    float*  G     = ws + 4194304;            // 32768 f
    ushort* WeffB = (ushort*)(ws + 4227072); // 20480 bf16
    ushort* qb    = (ushort*)(ws + 4237312); // 131072 bf16
    ushort* kb    = (ushort*)(ws + 4302848);
    ushort* vT    = (ushort*)(ws + 4368384); // 1048576 bf16
    float*  pm    = ws + 4892672;            // 65536 f
    float*  pl    = ws + 4958208;            // 65536 f  (total ~20.1 MB)

    gram_k <<<512, 256, 0, stream>>>(cnn, vit, part);
    gred_k <<<512, 64,  0, stream>>>(part, G);
    weff_k <<<20,  256, 0, stream>>>(G, Wq, Wk, Wv, gcnn, gvit, WeffB);
    qkv_k  <<<256, 256, 0, stream>>>(cnn, vit, WeffB, bq, bk, bv, qb, kb, vT);
    flash_k<<<512, 256, 0, stream>>>(qb, kb, vT, pOT, pm, pl);
    comb_k <<<256, 256, 0, stream>>>(pOT, pm, pl, cnn, gam, out);
}